// Round 2
// baseline (2324.000 us; speedup 1.0000x reference)
//
#include <hip/hip_runtime.h>

#define H 512
#define SEQ 256
#define BATCH 32
#define ROWS (BATCH * SEQ)   // 8192
#define G7 (7 * H)           // 3584
#define K3 (3 * H)           // 1536
#define KC 2048              // cat width: [h, hb, ha, x]
#define NLAYERS 7
#define LNEPS 1e-5f
#define MCHUNK 4096          // M-split for gate GEMM + pointwise

typedef __attribute__((ext_vector_type(8))) short s16x8;
typedef __attribute__((ext_vector_type(4))) float f32x4;

__device__ __forceinline__ short f2b(float f) {
  union { float f; unsigned u; } x; x.f = f;
  unsigned r = x.u + 0x7fffu + ((x.u >> 16) & 1u);
  return (short)(r >> 16);
}
__device__ __forceinline__ float b2f(short s) {
  union { unsigned u; float f; } x; x.u = ((unsigned)(unsigned short)s) << 16;
  return x.f;
}

__device__ __forceinline__ void gload_lds16(const void* g, void* l) {
  __builtin_amdgcn_global_load_lds(
      (const __attribute__((address_space(1))) void*)g,
      (__attribute__((address_space(3))) void*)l, 16, 0, 0);
}

// ---------------- WgT: [G7][KC] bf16 ; k<K3 from Wg[k][n], else We_gate[k-K3][n]
__global__ void make_WgT(const float* __restrict__ Wg, const float* __restrict__ Weg,
                         short* __restrict__ out) {
  long i = (long)blockIdx.x * 256 + threadIdx.x;
  if (i >= (long)G7 * KC) return;
  int n = (int)(i >> 11);
  int k = (int)(i & (KC - 1));
  float v = (k < K3) ? Wg[(long)k * G7 + n] : Weg[(long)(k - K3) * G7 + n];
  out[i] = f2b(v);
}

// ---------------- generic W[Kd][Nd] f32 -> out[Nd][Kd] bf16
__global__ void trans_w(const float* __restrict__ in, short* __restrict__ out,
                        int Kd, int Nd) {
  long i = (long)blockIdx.x * 256 + threadIdx.x;
  if (i >= (long)Kd * Nd) return;
  int n = (int)(i / Kd);
  int k = (int)(i - (long)n * Kd);
  out[i] = f2b(in[(long)k * Nd + n]);
}

// ---------------- prep: x = word*mask ; h = c0 = x (f32) ; cat x-part = bf16(x)
__global__ void prep(const float* __restrict__ word, const int* __restrict__ mask,
                     float* __restrict__ h, float* __restrict__ c0,
                     short* __restrict__ cat) {
  long i = (long)blockIdx.x * 256 + threadIdx.x;
  int row = (int)(i >> 9);
  int j = (int)(i & (H - 1));
  float msk = mask[row] ? 0.f : 1.f;
  float v = word[i] * msk;
  h[i] = v; c0[i] = v;
  cat[(long)row * KC + K3 + j] = f2b(v);
}

// ---------------- per layer: cat[:, 0:1536) = [h, hb, ha] bf16
__global__ __launch_bounds__(512) void build_cat(const float* __restrict__ h,
                                                 const int* __restrict__ mask,
                                                 short* __restrict__ cat) {
  int row = blockIdx.x;
  int s = row & (SEQ - 1);
  int j = threadIdx.x;
  float msk = mask[row] ? 0.f : 1.f;
  long rb = (long)row * H + j;
  float v = h[rb];
  float hm1 = (s >= 1) ? h[rb - H] : 0.f;
  float hm2 = (s >= 2) ? h[rb - 2 * H] : 0.f;
  float hp1 = (s <= SEQ - 2) ? h[rb + H] : 0.f;
  float hp2 = (s <= SEQ - 3) ? h[rb + 2 * H] : 0.f;
  long cb = (long)row * KC;
  cat[cb + j] = f2b(v);
  cat[cb + H + j] = f2b((hm1 + hm2) * msk);
  cat[cb + 2 * H + j] = f2b((hp1 + hp2) * msk);
}

// ---------------- bf16 MFMA GEMM, C = A[M,K](lda) * BT[N,K]^T, 128x128 tile, BK=32
// EPI 0: emb  = bf16(tanh(acc + bias[col]))
// EPI 1: gates = acc + bias[col]                      (f32)
// EPI 2: t1   = bf16(relu(acc + bias[col]))
// EPI 3: out  = acc + bias[col] + addF[row*N+col]     (f32)
template <int EPI>
__global__ __launch_bounds__(256) void gemm_bt(
    const short* __restrict__ A, int lda, const short* __restrict__ BT,
    int M, int N, int K,
    const float* __restrict__ bias,
    const float* __restrict__ addF,
    float* __restrict__ outF, short* __restrict__ outB) {
  __shared__ __align__(16) short As[128 * 32];
  __shared__ __align__(16) short Bs[128 * 32];
  const int nbn = N >> 7;
  const int bm = blockIdx.x / nbn;
  const int bn = blockIdx.x % nbn;
  const int tid = threadIdx.x;
  const int lane = tid & 63;
  const int wave = tid >> 6;
  const int wr = (wave >> 1) << 6;
  const int wc = (wave & 1) << 6;
  const int l15 = lane & 15;
  const int krow = (lane >> 4) << 3;

  f32x4 acc[4][4] = {};

  const long arow0 = (long)bm * 128;
  const long brow0 = (long)bn * 128;

  for (int k0 = 0; k0 < K; k0 += 32) {
#pragma unroll
    for (int i = 0; i < 2; ++i) {
      const int e = (i * 256 + tid) * 8;
      const int r = e >> 5, c = e & 31;
      gload_lds16(A + (arow0 + r) * lda + k0 + c, As + (long)(i * 256 + (wave << 6)) * 8);
      gload_lds16(BT + (brow0 + r) * K + k0 + c, Bs + (long)(i * 256 + (wave << 6)) * 8);
    }
    __syncthreads();
    s16x8 af[4], bfr[4];
#pragma unroll
    for (int m = 0; m < 4; ++m)
      af[m] = *(const s16x8*)(As + (wr + m * 16 + l15) * 32 + krow);
#pragma unroll
    for (int n = 0; n < 4; ++n)
      bfr[n] = *(const s16x8*)(Bs + (wc + n * 16 + l15) * 32 + krow);
#pragma unroll
    for (int m = 0; m < 4; ++m)
#pragma unroll
      for (int n = 0; n < 4; ++n)
        acc[m][n] = __builtin_amdgcn_mfma_f32_16x16x32_bf16(af[m], bfr[n], acc[m][n], 0, 0, 0);
    __syncthreads();
  }

#pragma unroll
  for (int m = 0; m < 4; ++m) {
#pragma unroll
    for (int n = 0; n < 4; ++n) {
#pragma unroll
      for (int j = 0; j < 4; ++j) {
        const long row = arow0 + wr + m * 16 + ((lane >> 4) << 2) + j;
        const long col = brow0 + wc + n * 16 + l15;
        const float v = acc[m][n][j];
        if (EPI == 0) {
          outB[row * N + col] = f2b(tanhf(v + bias[col]));
        } else if (EPI == 1) {
          outF[row * N + col] = v + bias[col];
        } else if (EPI == 2) {
          outB[row * N + col] = f2b(fmaxf(v + bias[col], 0.f));
        } else {
          outF[row * N + col] = v + bias[col] + addF[row * N + col];
        }
      }
    }
  }
}

// ---------------- per-row pointwise: 6 LayerNorms + gates + cell update
// gates holds MCHUNK local rows; global row = row0 + blockIdx.x
__global__ __launch_bounds__(512) void pointwise(
    const float* __restrict__ gates, const short* __restrict__ emb,
    const float* __restrict__ cin, float* __restrict__ cout,
    float* __restrict__ h, const int* __restrict__ mask,
    const float* __restrict__ lng, const float* __restrict__ lnb, int row0) {
  const int row = row0 + blockIdx.x;
  const int s = row & (SEQ - 1);
  const int tid = threadIdx.x;
  const int lane = tid & 63, wave = tid >> 6;
  const float msk = mask[row] ? 0.f : 1.f;
  const float* grow = gates + (long)blockIdx.x * G7;

  float g[7];
#pragma unroll
  for (int k = 0; k < 7; ++k) g[k] = grow[k * H + tid];

  const int cidx[6] = {0, 1, 2, 3, 4, 6};
  float red[12];
#pragma unroll
  for (int i = 0; i < 6; ++i) {
    float v = g[cidx[i]];
    red[i] = v; red[6 + i] = v * v;
  }
#pragma unroll
  for (int st = 32; st > 0; st >>= 1) {
#pragma unroll
    for (int i = 0; i < 12; ++i) red[i] += __shfl_xor(red[i], st, 64);
  }
  __shared__ float lred[8][12];
  __shared__ float fin[12];
  if (lane == 0) {
#pragma unroll
    for (int i = 0; i < 12; ++i) lred[wave][i] = red[i];
  }
  __syncthreads();
  if (tid < 12) {
    float a = 0.f;
#pragma unroll
    for (int w = 0; w < 8; ++w) a += lred[w][tid];
    fin[tid] = a;
  }
  __syncthreads();

  float ln[6];
#pragma unroll
  for (int i = 0; i < 6; ++i) {
    float mean = fin[i] * (1.f / (float)H);
    float var = fin[6 + i] * (1.f / (float)H) - mean * mean;
    float inv = rsqrtf(var + LNEPS);
    int pidx = (i < 5) ? i : 5;
    ln[i] = (g[cidx[i]] - mean) * inv * lng[pidx * H + tid] + lnb[pidx * H + tid];
  }
  float gfl = ln[0], gfr = ln[1], gfc = ln[2];
  float gi = 1.f / (1.f + expf(-ln[3]));
  float ge = 1.f / (1.f + expf(-ln[4]));
  float go = 1.f / (1.f + expf(-ln[5]));
  float gw = tanhf(g[5]) + ge * b2f(emb[(long)row * H + tid]);

  float mx = fmaxf(gfl, fmaxf(gfr, gfc));
  float e0 = expf(gfl - mx), e1 = expf(gfr - mx), e2 = expf(gfc - mx);
  float inv3 = 1.f / (e0 + e1 + e2);
  float f0 = e0 * inv3, f1 = e1 * inv3, f2 = e2 * inv3;

  const long rb = (long)row * H + tid;
  float cc = cin[rb];
  float cm1 = (s >= 1) ? cin[rb - H] : 0.f;
  float cm2 = (s >= 2) ? cin[rb - 2 * H] : 0.f;
  float cp1 = (s <= SEQ - 2) ? cin[rb + H] : 0.f;
  float cp2 = (s <= SEQ - 3) ? cin[rb + 2 * H] : 0.f;
  float cbv = (cm1 + cm2) * msk, cav = (cp1 + cp2) * msk;
  float lc = cbv * f0 + cav * f1 + cc * f2;
  float cn = (lc * (1.f - gi) + gw * gi) * msk;
  float hv = go * tanhf(cn) * msk;
  cout[rb] = cn;
  h[rb] = hv;
}

// ---------------- final LN over h -> hn (f32 + bf16)
__global__ __launch_bounds__(512) void ln_final(
    const float* __restrict__ h, const float* __restrict__ g6,
    const float* __restrict__ b6, float* __restrict__ hnF,
    short* __restrict__ hnB) {
  const int row = blockIdx.x;
  const int tid = threadIdx.x;
  const int lane = tid & 63, wave = tid >> 6;
  const long rb = (long)row * H + tid;
  float v = h[rb];
  float r0 = v, r1 = v * v;
#pragma unroll
  for (int st = 32; st > 0; st >>= 1) {
    r0 += __shfl_xor(r0, st, 64);
    r1 += __shfl_xor(r1, st, 64);
  }
  __shared__ float lred[8][2];
  __shared__ float fin[2];
  if (lane == 0) { lred[wave][0] = r0; lred[wave][1] = r1; }
  __syncthreads();
  if (tid < 2) {
    float a = 0.f;
#pragma unroll
    for (int w = 0; w < 8; ++w) a += lred[w][tid];
    fin[tid] = a;
  }
  __syncthreads();
  float mean = fin[0] * (1.f / (float)H);
  float var = fin[1] * (1.f / (float)H) - mean * mean;
  float inv = rsqrtf(var + LNEPS);
  float o = (v - mean) * inv * g6[tid] + b6[tid];
  hnF[rb] = o;
  hnB[rb] = f2b(o);
}

extern "C" void kernel_launch(void* const* d_in, const int* in_sizes, int n_in,
                              void* d_out, int out_size, void* d_ws, size_t ws_size,
                              hipStream_t stream) {
  const float* word = (const float*)d_in[0];
  const int* mask = (const int*)d_in[1];
  const float* Wg = (const float*)d_in[2];
  const float* bg = (const float*)d_in[3];
  const float* We_gate = (const float*)d_in[4];
  const float* We_trans = (const float*)d_in[5];
  const float* be_trans = (const float*)d_in[6];
  const float* W1 = (const float*)d_in[7];
  const float* b1 = (const float*)d_in[8];
  const float* W2 = (const float*)d_in[9];
  const float* b2 = (const float*)d_in[10];
  const float* ln_g = (const float*)d_in[11];
  const float* ln_b = (const float*)d_in[12];
  float* out = (float*)d_out;

  char* p = (char*)d_ws;
  auto take = [&](size_t bytes) -> char* {
    char* r = p;
    p += (bytes + 255) & ~(size_t)255;
    return r;
  };
  short* WgT   = (short*)take((size_t)G7 * KC * 2);        // 14.7 MB
  short* WeTt  = (short*)take((size_t)H * H * 2);          // 0.5 MB
  short* W1T   = (short*)take((size_t)(2 * H) * H * 2);    // 1 MB
  short* W2T   = (short*)take((size_t)H * (2 * H) * 2);    // 1 MB
  short* cat   = (short*)take((size_t)ROWS * KC * 2);      // 32 MB
  float* gates = (float*)take((size_t)MCHUNK * G7 * 4);    // 56 MB
  short* emb   = (short*)take((size_t)ROWS * H * 2);       // 8 MB
  float* h     = (float*)take((size_t)ROWS * H * 4);       // 16 MB
  float* c0    = (float*)take((size_t)ROWS * H * 4);       // 16 MB
  float* c1    = (float*)take((size_t)ROWS * H * 4);       // 16 MB
  // post-loop aliases (regions dead after layer loop):
  float* hnF = c0;
  short* hnB = emb;
  short* t1  = (short*)gates;

  {
    long n = (long)G7 * KC;
    make_WgT<<<(int)((n + 255) / 256), 256, 0, stream>>>(Wg, We_gate, WgT);
    n = (long)H * H;
    trans_w<<<(int)((n + 255) / 256), 256, 0, stream>>>(We_trans, WeTt, H, H);
    n = (long)H * 2 * H;
    trans_w<<<(int)((n + 255) / 256), 256, 0, stream>>>(W1, W1T, H, 2 * H);
    n = (long)2 * H * H;
    trans_w<<<(int)((n + 255) / 256), 256, 0, stream>>>(W2, W2T, 2 * H, H);
  }

  prep<<<ROWS * H / 256, 256, 0, stream>>>(word, mask, h, c0, cat);

  // emb = bf16(tanh(x @ We_trans + be)) ; A = x-part of cat (lda=KC)
  gemm_bt<0><<<(ROWS / 128) * (H / 128), 256, 0, stream>>>(
      cat + K3, KC, WeTt, ROWS, H, H, be_trans, nullptr, nullptr, emb);

  float* cin = c0;
  float* cout = c1;
  for (int l = 0; l < NLAYERS; ++l) {
    build_cat<<<ROWS, 512, 0, stream>>>(h, mask, cat);
    for (int ch = 0; ch < ROWS / MCHUNK; ++ch) {
      gemm_bt<1><<<(MCHUNK / 128) * (G7 / 128), 256, 0, stream>>>(
          cat + (long)ch * MCHUNK * KC, KC, WgT, MCHUNK, G7, KC, bg,
          nullptr, gates, nullptr);
      pointwise<<<MCHUNK, 512, 0, stream>>>(gates, emb, cin, cout, h, mask,
                                            ln_g, ln_b, ch * MCHUNK);
    }
    float* tmp = cin; cin = cout; cout = tmp;
  }

  ln_final<<<ROWS, 512, 0, stream>>>(h, ln_g + 6 * H, ln_b + 6 * H, hnF, hnB);
  gemm_bt<2><<<(ROWS / 128) * ((2 * H) / 128), 256, 0, stream>>>(
      hnB, H, W1T, ROWS, 2 * H, H, b1, nullptr, nullptr, t1);
  gemm_bt<3><<<(ROWS / 128) * (H / 128), 256, 0, stream>>>(
      t1, 2 * H, W2T, ROWS, H, 2 * H, b2, hnF, out, nullptr);
}

// Round 3
// 1707.633 us; speedup vs baseline: 1.3609x; 1.3609x over previous
//
#include <hip/hip_runtime.h>

#define H 512
#define SEQ 256
#define BATCH 32
#define ROWS (BATCH * SEQ)   // 8192
#define G7 (7 * H)           // 3584
#define K3 (3 * H)           // 1536
#define KC 2048              // cat width: [h, hb, ha, x]
#define NLAYERS 7
#define LNEPS 1e-5f
#define MCHUNK 4096          // M-split for gate GEMM + pointwise

typedef __attribute__((ext_vector_type(8))) short s16x8;
typedef __attribute__((ext_vector_type(4))) float f32x4;

__device__ __forceinline__ short f2b(float f) {
  union { float f; unsigned u; } x; x.f = f;
  unsigned r = x.u + 0x7fffu + ((x.u >> 16) & 1u);
  return (short)(r >> 16);
}
__device__ __forceinline__ float b2f(short s) {
  union { unsigned u; float f; } x; x.u = ((unsigned)(unsigned short)s) << 16;
  return x.f;
}

__device__ __forceinline__ void gload_lds16(const void* g, void* l) {
  __builtin_amdgcn_global_load_lds(
      (const __attribute__((address_space(1))) void*)g,
      (__attribute__((address_space(3))) void*)l, 16, 0, 0);
}

#define SFEN() __builtin_amdgcn_sched_barrier(0)
#define SBAR() __builtin_amdgcn_s_barrier()

// ---------------- coalesced LDS-tiled builder for WgT [G7][KC] bf16
// src(k, n) = k<K3 ? Wg[k][n] : We_gate[k-K3][n]  (both [*][G7] f32)
__global__ __launch_bounds__(256) void make_WgT2(const float* __restrict__ Wg,
                                                 const float* __restrict__ Weg,
                                                 short* __restrict__ out) {
  __shared__ float t[32][33];
  const int nbn = G7 / 32;
  const int bn = blockIdx.x % nbn, bk = blockIdx.x / nbn;
  const int n0 = bn * 32, k0 = bk * 32;
  const int tx = threadIdx.x & 31, ty = threadIdx.x >> 5;  // ty 0..7
#pragma unroll
  for (int i = 0; i < 4; ++i) {
    const int k = k0 + ty + i * 8;
    t[ty + i * 8][tx] = (k < K3) ? Wg[(long)k * G7 + n0 + tx]
                                 : Weg[(long)(k - K3) * G7 + n0 + tx];
  }
  __syncthreads();
#pragma unroll
  for (int i = 0; i < 4; ++i) {
    const int n = ty + i * 8;
    out[(long)(n0 + n) * KC + k0 + tx] = f2b(t[tx][n]);
  }
}

// ---------------- coalesced tiled transpose: W[Kd][Nd] f32 -> out[Nd][Kd] bf16
__global__ __launch_bounds__(256) void trans_w2(const float* __restrict__ in,
                                                short* __restrict__ out,
                                                int Kd, int Nd) {
  __shared__ float t[32][33];
  const int nbn = Nd / 32;
  const int bn = blockIdx.x % nbn, bk = blockIdx.x / nbn;
  const int n0 = bn * 32, k0 = bk * 32;
  const int tx = threadIdx.x & 31, ty = threadIdx.x >> 5;
#pragma unroll
  for (int i = 0; i < 4; ++i)
    t[ty + i * 8][tx] = in[(long)(k0 + ty + i * 8) * Nd + n0 + tx];
  __syncthreads();
#pragma unroll
  for (int i = 0; i < 4; ++i) {
    const int n = ty + i * 8;
    out[(long)(n0 + n) * Kd + k0 + tx] = f2b(t[tx][n]);
  }
}

// ---------------- prep: x = word*mask ; h = c0 = x (f32) ; cat x-part = bf16(x)
__global__ void prep(const float* __restrict__ word, const int* __restrict__ mask,
                     float* __restrict__ h, float* __restrict__ c0,
                     short* __restrict__ cat) {
  long i = (long)blockIdx.x * 256 + threadIdx.x;
  int row = (int)(i >> 9);
  int j = (int)(i & (H - 1));
  float msk = mask[row] ? 0.f : 1.f;
  float v = word[i] * msk;
  h[i] = v; c0[i] = v;
  cat[(long)row * KC + K3 + j] = f2b(v);
}

// ---------------- per layer: cat[:, 0:1536) = [h, hb, ha] bf16
__global__ __launch_bounds__(512) void build_cat(const float* __restrict__ h,
                                                 const int* __restrict__ mask,
                                                 short* __restrict__ cat) {
  int row = blockIdx.x;
  int s = row & (SEQ - 1);
  int j = threadIdx.x;
  float msk = mask[row] ? 0.f : 1.f;
  long rb = (long)row * H + j;
  float v = h[rb];
  float hm1 = (s >= 1) ? h[rb - H] : 0.f;
  float hm2 = (s >= 2) ? h[rb - 2 * H] : 0.f;
  float hp1 = (s <= SEQ - 2) ? h[rb + H] : 0.f;
  float hp2 = (s <= SEQ - 3) ? h[rb + 2 * H] : 0.f;
  long cb = (long)row * KC;
  cat[cb + j] = f2b(v);
  cat[cb + H + j] = f2b((hm1 + hm2) * msk);
  cat[cb + 2 * H + j] = f2b((hp1 + hp2) * msk);
}

// =====================================================================
// 256x256 8-phase bf16 MFMA GEMM (T2 swizzle + T3/T4 counted vmcnt + T5)
// C = A[M,K](lda) * BT[N,K](ldb)^T ; out = acc + bias[col] (f32)
// 512 threads = 8 waves (2M x 4N); BK=64 (2 k-halves of 32); LDS 128 KiB.
// =====================================================================
#define MFMA16(AF, BF, MOFF)                                              \
  {                                                                       \
    _Pragma("unroll") for (int mf_ = 0; mf_ < 4; ++mf_)                   \
      _Pragma("unroll") for (int nf_ = 0; nf_ < 4; ++nf_)                 \
        acc[(MOFF) + mf_][nf_] = __builtin_amdgcn_mfma_f32_16x16x32_bf16( \
            AF[mf_], BF[nf_], acc[(MOFF) + mf_][nf_], 0, 0, 0);           \
  }

__global__ __launch_bounds__(512) void gemm256_gate(
    const short* __restrict__ A, int lda,
    const short* __restrict__ BT, int ldb,
    int N, int K, const float* __restrict__ bias,
    float* __restrict__ outF) {
  __shared__ __align__(16) short lds[65536];  // 128 KiB
  const int nbn = N >> 8;
  int bid = blockIdx.x;
  const int nwg = gridDim.x;
  if ((nwg & 7) == 0) {  // bijective XCD swizzle
    const int cpx = nwg >> 3;
    bid = (bid & 7) * cpx + (bid >> 3);
  }
  const int bm = bid / nbn, bn = bid % nbn;
  const int tid = threadIdx.x, lane = tid & 63, wave = tid >> 6;
  const int wm = wave >> 2, wn = wave & 3;
  const int l15 = lane & 15, l4 = lane >> 4;
  const long arow0 = (long)bm * 256, brow0 = (long)bn * 256;
  const int NT = K >> 6;

  f32x4 acc[8][4] = {};

  // stage one 16KB k-half: mat(0=A,1=B), kh, source tile tsrc, dest buf sbuf.
  // Linear LDS dest; global source pre-swizzled so swizzled reads see (r,c).
  auto STAGE = [&](int mat, int kh, int tsrc, int sbuf) {
    const short* gb = mat ? BT : A;
    const int ld = mat ? ldb : lda;
    const long r0 = mat ? brow0 : arow0;
    const int kb = tsrc * 64 + kh * 32;
#pragma unroll
    for (int i = 0; i < 2; ++i) {
      const int L16 = i * 512 + tid;          // 16B-granule index in half
      const int r = L16 >> 2;                 // row 0..255
      const int cs = ((L16 & 3) << 4) ^ (((r >> 1) & 3) << 4);  // swz byte col
      gload_lds16(gb + (r0 + r) * ld + kb + (cs >> 1),
                  lds + sbuf * 32768 + mat * 16384 + kh * 8192 +
                      (i * 512 + (wave << 6)) * 8);
    }
  };
  auto LDA4 = [&](int sbuf, int ks, int mh, s16x8* f) {
#pragma unroll
    for (int mf = 0; mf < 4; ++mf) {
      const int r = wm * 128 + mh * 64 + mf * 16 + l15;
      const int c = (l4 << 4) ^ (((r >> 1) & 3) << 4);
      f[mf] = *(const s16x8*)(lds + sbuf * 32768 + ks * 8192 + r * 32 + (c >> 1));
    }
  };
  auto LDB4 = [&](int sbuf, int ks, s16x8* f) {
#pragma unroll
    for (int nf = 0; nf < 4; ++nf) {
      const int r = wn * 64 + nf * 16 + l15;
      const int c = (l4 << 4) ^ (((r >> 1) & 3) << 4);
      f[nf] = *(const s16x8*)(lds + sbuf * 32768 + 16384 + ks * 8192 + r * 32 + (c >> 1));
    }
  };

  // prologue: tile0 (4 halves) + tile1 k0-halves; then counted wait
  STAGE(0, 0, 0, 0); STAGE(1, 0, 0, 0); STAGE(0, 1, 0, 0); STAGE(1, 1, 0, 0);
  {
    const int t1 = (NT > 1) ? 1 : 0;
    STAGE(0, 0, t1, 1); STAGE(1, 0, t1, 1);
  }
  SFEN();
  asm volatile("s_waitcnt vmcnt(4)" ::: "memory");
  SBAR();
  SFEN();

  for (int t = 0; t < NT; ++t) {
    const int cb = t & 1, nb = cb ^ 1;
    const int t1 = (t + 1 < NT) ? t + 1 : NT - 1;
    const int t2 = (t + 2 < NT) ? t + 2 : NT - 1;
    s16x8 fa[4], fb0[4], fb1[4];

    // ---- ph0: (k-half 0, m-half 0); stage A_k1(t+1)
    LDA4(cb, 0, 0, fa); LDB4(cb, 0, fb0);
    STAGE(0, 1, t1, nb);
    SFEN(); SBAR();
    asm volatile("s_waitcnt lgkmcnt(0)" ::: "memory");
    SFEN();
    __builtin_amdgcn_s_setprio(1);
    MFMA16(fa, fb0, 0);
    __builtin_amdgcn_s_setprio(0);
    SFEN(); SBAR(); SFEN();

    // ---- ph1: (k0, m1); stage B_k1(t+1)
    LDA4(cb, 0, 1, fa);
    STAGE(1, 1, t1, nb);
    SFEN(); SBAR();
    asm volatile("s_waitcnt lgkmcnt(0)" ::: "memory");
    SFEN();
    __builtin_amdgcn_s_setprio(1);
    MFMA16(fa, fb0, 4);
    __builtin_amdgcn_s_setprio(0);
    SFEN(); SBAR(); SFEN();

    // ---- ph2: (k1, m0); stage A_k0(t+2) into current buf (reads done ph1)
    LDA4(cb, 1, 0, fa); LDB4(cb, 1, fb1);
    STAGE(0, 0, t2, cb);
    SFEN(); SBAR();
    asm volatile("s_waitcnt lgkmcnt(0)" ::: "memory");
    SFEN();
    __builtin_amdgcn_s_setprio(1);
    MFMA16(fa, fb1, 0);
    __builtin_amdgcn_s_setprio(0);
    SFEN(); SBAR(); SFEN();

    // ---- ph3: (k1, m1); stage B_k0(t+2)
    LDA4(cb, 1, 1, fa);
    STAGE(1, 0, t2, cb);
    SFEN(); SBAR();
    asm volatile("s_waitcnt lgkmcnt(0)" ::: "memory");
    SFEN();
    __builtin_amdgcn_s_setprio(1);
    MFMA16(fa, fb1, 4);
    __builtin_amdgcn_s_setprio(0);
    // tile-end: counted vmcnt (never 0) + barrier -> next tile fully staged
    SFEN();
    asm volatile("s_waitcnt vmcnt(4)" ::: "memory");
    SBAR();
    SFEN();
  }
  asm volatile("s_waitcnt vmcnt(0)" ::: "memory");

  // epilogue: C = acc + bias
#pragma unroll
  for (int mi = 0; mi < 8; ++mi) {
#pragma unroll
    for (int nf = 0; nf < 4; ++nf) {
#pragma unroll
      for (int j = 0; j < 4; ++j) {
        const long row = arow0 + wm * 128 + mi * 16 + l4 * 4 + j;
        const long col = brow0 + wn * 64 + nf * 16 + l15;
        outF[row * N + col] = acc[mi][nf][j] + bias[col];
      }
    }
  }
}

// ---------------- 128x128 bf16 MFMA GEMM (small GEMMs), proven in round 2
// EPI 0: emb  = bf16(tanh(acc + bias[col]))
// EPI 2: t1   = bf16(relu(acc + bias[col]))
// EPI 3: out  = acc + bias[col] + addF[row*N+col]     (f32)
template <int EPI>
__global__ __launch_bounds__(256) void gemm_bt(
    const short* __restrict__ A, int lda, const short* __restrict__ BT,
    int M, int N, int K,
    const float* __restrict__ bias,
    const float* __restrict__ addF,
    float* __restrict__ outF, short* __restrict__ outB) {
  __shared__ __align__(16) short As[128 * 32];
  __shared__ __align__(16) short Bs[128 * 32];
  const int nbn = N >> 7;
  const int bm = blockIdx.x / nbn;
  const int bn = blockIdx.x % nbn;
  const int tid = threadIdx.x;
  const int lane = tid & 63;
  const int wave = tid >> 6;
  const int wr = (wave >> 1) << 6;
  const int wc = (wave & 1) << 6;
  const int l15 = lane & 15;
  const int krow = (lane >> 4) << 3;

  f32x4 acc[4][4] = {};

  const long arow0 = (long)bm * 128;
  const long brow0 = (long)bn * 128;

  for (int k0 = 0; k0 < K; k0 += 32) {
#pragma unroll
    for (int i = 0; i < 2; ++i) {
      const int e = (i * 256 + tid) * 8;
      const int r = e >> 5, c = e & 31;
      gload_lds16(A + (arow0 + r) * lda + k0 + c, As + (long)(i * 256 + (wave << 6)) * 8);
      gload_lds16(BT + (brow0 + r) * K + k0 + c, Bs + (long)(i * 256 + (wave << 6)) * 8);
    }
    __syncthreads();
    s16x8 af[4], bfr[4];
#pragma unroll
    for (int m = 0; m < 4; ++m)
      af[m] = *(const s16x8*)(As + (wr + m * 16 + l15) * 32 + krow);
#pragma unroll
    for (int n = 0; n < 4; ++n)
      bfr[n] = *(const s16x8*)(Bs + (wc + n * 16 + l15) * 32 + krow);
#pragma unroll
    for (int m = 0; m < 4; ++m)
#pragma unroll
      for (int n = 0; n < 4; ++n)
        acc[m][n] = __builtin_amdgcn_mfma_f32_16x16x32_bf16(af[m], bfr[n], acc[m][n], 0, 0, 0);
    __syncthreads();
  }

#pragma unroll
  for (int m = 0; m < 4; ++m) {
#pragma unroll
    for (int n = 0; n < 4; ++n) {
#pragma unroll
      for (int j = 0; j < 4; ++j) {
        const long row = arow0 + wr + m * 16 + ((lane >> 4) << 2) + j;
        const long col = brow0 + wc + n * 16 + l15;
        const float v = acc[m][n][j];
        if (EPI == 0) {
          outB[row * N + col] = f2b(tanhf(v + bias[col]));
        } else if (EPI == 2) {
          outB[row * N + col] = f2b(fmaxf(v + bias[col], 0.f));
        } else {
          outF[row * N + col] = v + bias[col] + addF[row * N + col];
        }
      }
    }
  }
}

// ---------------- per-row pointwise: 6 LayerNorms + gates + cell update
__global__ __launch_bounds__(512) void pointwise(
    const float* __restrict__ gates, const short* __restrict__ emb,
    const float* __restrict__ cin, float* __restrict__ cout,
    float* __restrict__ h, const int* __restrict__ mask,
    const float* __restrict__ lng, const float* __restrict__ lnb, int row0) {
  const int row = row0 + blockIdx.x;
  const int s = row & (SEQ - 1);
  const int tid = threadIdx.x;
  const int lane = tid & 63, wave = tid >> 6;
  const float msk = mask[row] ? 0.f : 1.f;
  const float* grow = gates + (long)blockIdx.x * G7;

  float g[7];
#pragma unroll
  for (int k = 0; k < 7; ++k) g[k] = grow[k * H + tid];

  const int cidx[6] = {0, 1, 2, 3, 4, 6};
  float red[12];
#pragma unroll
  for (int i = 0; i < 6; ++i) {
    float v = g[cidx[i]];
    red[i] = v; red[6 + i] = v * v;
  }
#pragma unroll
  for (int st = 32; st > 0; st >>= 1) {
#pragma unroll
    for (int i = 0; i < 12; ++i) red[i] += __shfl_xor(red[i], st, 64);
  }
  __shared__ float lred[8][12];
  __shared__ float fin[12];
  if (lane == 0) {
#pragma unroll
    for (int i = 0; i < 12; ++i) lred[wave][i] = red[i];
  }
  __syncthreads();
  if (tid < 12) {
    float a = 0.f;
#pragma unroll
    for (int w = 0; w < 8; ++w) a += lred[w][tid];
    fin[tid] = a;
  }
  __syncthreads();

  float ln[6];
#pragma unroll
  for (int i = 0; i < 6; ++i) {
    float mean = fin[i] * (1.f / (float)H);
    float var = fin[6 + i] * (1.f / (float)H) - mean * mean;
    float inv = rsqrtf(var + LNEPS);
    int pidx = (i < 5) ? i : 5;
    ln[i] = (g[cidx[i]] - mean) * inv * lng[pidx * H + tid] + lnb[pidx * H + tid];
  }
  float gfl = ln[0], gfr = ln[1], gfc = ln[2];
  float gi = 1.f / (1.f + expf(-ln[3]));
  float ge = 1.f / (1.f + expf(-ln[4]));
  float go = 1.f / (1.f + expf(-ln[5]));
  float gw = tanhf(g[5]) + ge * b2f(emb[(long)row * H + tid]);

  float mx = fmaxf(gfl, fmaxf(gfr, gfc));
  float e0 = expf(gfl - mx), e1 = expf(gfr - mx), e2 = expf(gfc - mx);
  float inv3 = 1.f / (e0 + e1 + e2);
  float f0 = e0 * inv3, f1 = e1 * inv3, f2 = e2 * inv3;

  const long rb = (long)row * H + tid;
  float cc = cin[rb];
  float cm1 = (s >= 1) ? cin[rb - H] : 0.f;
  float cm2 = (s >= 2) ? cin[rb - 2 * H] : 0.f;
  float cp1 = (s <= SEQ - 2) ? cin[rb + H] : 0.f;
  float cp2 = (s <= SEQ - 3) ? cin[rb + 2 * H] : 0.f;
  float cbv = (cm1 + cm2) * msk, cav = (cp1 + cp2) * msk;
  float lc = cbv * f0 + cav * f1 + cc * f2;
  float cn = (lc * (1.f - gi) + gw * gi) * msk;
  float hv = go * tanhf(cn) * msk;
  cout[rb] = cn;
  h[rb] = hv;
}

// ---------------- final LN over h -> hn (f32 + bf16)
__global__ __launch_bounds__(512) void ln_final(
    const float* __restrict__ h, const float* __restrict__ g6,
    const float* __restrict__ b6, float* __restrict__ hnF,
    short* __restrict__ hnB) {
  const int row = blockIdx.x;
  const int tid = threadIdx.x;
  const int lane = tid & 63, wave = tid >> 6;
  const long rb = (long)row * H + tid;
  float v = h[rb];
  float r0 = v, r1 = v * v;
#pragma unroll
  for (int st = 32; st > 0; st >>= 1) {
    r0 += __shfl_xor(r0, st, 64);
    r1 += __shfl_xor(r1, st, 64);
  }
  __shared__ float lred[8][2];
  __shared__ float fin[2];
  if (lane == 0) { lred[wave][0] = r0; lred[wave][1] = r1; }
  __syncthreads();
  if (tid < 2) {
    float a = 0.f;
#pragma unroll
    for (int w = 0; w < 8; ++w) a += lred[w][tid];
    fin[tid] = a;
  }
  __syncthreads();
  float mean = fin[0] * (1.f / (float)H);
  float var = fin[1] * (1.f / (float)H) - mean * mean;
  float inv = rsqrtf(var + LNEPS);
  float o = (v - mean) * inv * g6[tid] + b6[tid];
  hnF[rb] = o;
  hnB[rb] = f2b(o);
}

extern "C" void kernel_launch(void* const* d_in, const int* in_sizes, int n_in,
                              void* d_out, int out_size, void* d_ws, size_t ws_size,
                              hipStream_t stream) {
  const float* word = (const float*)d_in[0];
  const int* mask = (const int*)d_in[1];
  const float* Wg = (const float*)d_in[2];
  const float* bg = (const float*)d_in[3];
  const float* We_gate = (const float*)d_in[4];
  const float* We_trans = (const float*)d_in[5];
  const float* be_trans = (const float*)d_in[6];
  const float* W1 = (const float*)d_in[7];
  const float* b1 = (const float*)d_in[8];
  const float* W2 = (const float*)d_in[9];
  const float* b2 = (const float*)d_in[10];
  const float* ln_g = (const float*)d_in[11];
  const float* ln_b = (const float*)d_in[12];
  float* out = (float*)d_out;

  char* p = (char*)d_ws;
  auto take = [&](size_t bytes) -> char* {
    char* r = p;
    p += (bytes + 255) & ~(size_t)255;
    return r;
  };
  short* WgT   = (short*)take((size_t)G7 * KC * 2);        // 14.7 MB
  short* WeTt  = (short*)take((size_t)H * H * 2);          // 0.5 MB
  short* W1T   = (short*)take((size_t)(2 * H) * H * 2);    // 1 MB
  short* W2T   = (short*)take((size_t)H * (2 * H) * 2);    // 1 MB
  short* cat   = (short*)take((size_t)ROWS * KC * 2);      // 32 MB
  float* gates = (float*)take((size_t)MCHUNK * G7 * 4);    // 56 MB
  short* emb   = (short*)take((size_t)ROWS * H * 2);       // 8 MB
  float* h     = (float*)take((size_t)ROWS * H * 4);       // 16 MB
  float* c0    = (float*)take((size_t)ROWS * H * 4);       // 16 MB
  float* c1    = (float*)take((size_t)ROWS * H * 4);       // 16 MB
  // post-loop aliases (regions dead after layer loop):
  float* hnF = c0;
  short* hnB = emb;
  short* t1  = (short*)gates;

  {
    long n = (long)G7 * KC;
    make_WgT2<<<(int)(n / (32 * 32)), 256, 0, stream>>>(Wg, We_gate, WgT);
    n = (long)H * H;
    trans_w2<<<(int)(n / (32 * 32)), 256, 0, stream>>>(We_trans, WeTt, H, H);
    n = (long)H * 2 * H;
    trans_w2<<<(int)(n / (32 * 32)), 256, 0, stream>>>(W1, W1T, H, 2 * H);
    n = (long)2 * H * H;
    trans_w2<<<(int)(n / (32 * 32)), 256, 0, stream>>>(W2, W2T, 2 * H, H);
  }

  prep<<<ROWS * H / 256, 256, 0, stream>>>(word, mask, h, c0, cat);

  // emb = bf16(tanh(x @ We_trans + be)) ; A = x-part of cat (lda=KC)
  gemm_bt<0><<<(ROWS / 128) * (H / 128), 256, 0, stream>>>(
      cat + K3, KC, WeTt, ROWS, H, H, be_trans, nullptr, nullptr, emb);

  float* cin = c0;
  float* cout = c1;
  for (int l = 0; l < NLAYERS; ++l) {
    build_cat<<<ROWS, 512, 0, stream>>>(h, mask, cat);
    for (int ch = 0; ch < ROWS / MCHUNK; ++ch) {
      gemm256_gate<<<(MCHUNK / 256) * (G7 / 256), 512, 0, stream>>>(
          cat + (long)ch * MCHUNK * KC, KC, WgT, KC, G7, KC, bg, gates);
      pointwise<<<MCHUNK, 512, 0, stream>>>(gates, emb, cin, cout, h, mask,
                                            ln_g, ln_b, ch * MCHUNK);
    }
    float* tmp = cin; cin = cout; cout = tmp;
  }

  ln_final<<<ROWS, 512, 0, stream>>>(h, ln_g + 6 * H, ln_b + 6 * H, hnF, hnB);
  gemm_bt<2><<<(ROWS / 128) * ((2 * H) / 128), 256, 0, stream>>>(
      hnB, H, W1T, ROWS, 2 * H, H, b1, nullptr, nullptr, t1);
  gemm_bt<3><<<(ROWS / 128) * (H / 128), 256, 0, stream>>>(
      t1, 2 * H, W2T, ROWS, H, 2 * H, b2, hnF, out, nullptr);
}

// Round 6
// 1610.266 us; speedup vs baseline: 1.4432x; 1.0605x over previous
//
#include <hip/hip_runtime.h>

#define H 512
#define SEQ 256
#define BATCH 32
#define ROWS (BATCH * SEQ)   // 8192
#define G7 (7 * H)           // 3584
#define K3 (3 * H)           // 1536
#define KC 2048              // cat width: [h, hb, ha, x]
#define NLAYERS 7
#define LNEPS 1e-5f

typedef __attribute__((ext_vector_type(8))) short s16x8;
typedef __attribute__((ext_vector_type(4))) float f32x4;

__device__ __forceinline__ short f2b(float f) {
  union { float f; unsigned u; } x; x.f = f;
  unsigned r = x.u + 0x7fffu + ((x.u >> 16) & 1u);
  return (short)(r >> 16);
}
__device__ __forceinline__ float b2f(short s) {
  union { unsigned u; float f; } x; x.u = ((unsigned)(unsigned short)s) << 16;
  return x.f;
}

__device__ __forceinline__ void gload_lds16(const void* g, void* l) {
  __builtin_amdgcn_global_load_lds(
      (const __attribute__((address_space(1))) void*)g,
      (__attribute__((address_space(3))) void*)l, 16, 0, 0);
}

#define SFEN() __builtin_amdgcn_sched_barrier(0)
#define SBAR() __builtin_amdgcn_s_barrier()

// ---------------- fused weight transposes (one dispatch)
// block ranges: [0,7168) WgT ; [7168,7424) WeTt ; [7424,7936) W1T ; [7936,8448) W2T
__global__ __launch_bounds__(256) void trans_fused(
    const float* __restrict__ Wg, const float* __restrict__ Weg,
    const float* __restrict__ Wet, const float* __restrict__ W1,
    const float* __restrict__ W2,
    short* __restrict__ WgT, short* __restrict__ WeTt,
    short* __restrict__ W1T, short* __restrict__ W2T) {
  __shared__ float t[32][33];
  int b = blockIdx.x;
  const float *s1, *s2; short* o; int Kd, Nd, bound;
  if (b < 7168)      { s1 = Wg;  s2 = Weg; o = WgT;  Kd = KC;   Nd = G7;   bound = K3; }
  else if (b < 7424) { b -= 7168; s1 = s2 = Wet; o = WeTt; Kd = 512;  Nd = 512;  bound = 1 << 30; }
  else if (b < 7936) { b -= 7424; s1 = s2 = W1;  o = W1T;  Kd = 512;  Nd = 1024; bound = 1 << 30; }
  else               { b -= 7936; s1 = s2 = W2;  o = W2T;  Kd = 1024; Nd = 512;  bound = 1 << 30; }
  const int nbn = Nd / 32;
  const int bn = b % nbn, bk = b / nbn;
  const int n0 = bn * 32, k0 = bk * 32;
  const int tx = threadIdx.x & 31, ty = threadIdx.x >> 5;  // ty 0..7
#pragma unroll
  for (int i = 0; i < 4; ++i) {
    const int k = k0 + ty + i * 8;
    t[ty + i * 8][tx] = (k < bound) ? s1[(long)k * Nd + n0 + tx]
                                    : s2[(long)(k - K3) * Nd + n0 + tx];
  }
  __syncthreads();
#pragma unroll
  for (int i = 0; i < 4; ++i) {
    const int n = ty + i * 8;
    o[(long)(n0 + n) * Kd + k0 + tx] = f2b(t[tx][n]);
  }
}

// ---------------- prep: x = word*mask ; h = c0 = x (f32) ; cat x-part = bf16(x)
__global__ void prep(const float* __restrict__ word, const int* __restrict__ mask,
                     float* __restrict__ h, float* __restrict__ c0,
                     short* __restrict__ cat) {
  long i = (long)blockIdx.x * 256 + threadIdx.x;
  int row = (int)(i >> 9);
  int j = (int)(i & (H - 1));
  float msk = mask[row] ? 0.f : 1.f;
  float v = word[i] * msk;
  h[i] = v; c0[i] = v;
  cat[(long)row * KC + K3 + j] = f2b(v);
}

// ---------------- per layer: cat[:, 0:1536) = [h, hb, ha] bf16
__global__ __launch_bounds__(512) void build_cat(const float* __restrict__ h,
                                                 const int* __restrict__ mask,
                                                 short* __restrict__ cat) {
  int row = blockIdx.x;
  int s = row & (SEQ - 1);
  int j = threadIdx.x;
  float msk = mask[row] ? 0.f : 1.f;
  long rb = (long)row * H + j;
  float v = h[rb];
  float hm1 = (s >= 1) ? h[rb - H] : 0.f;
  float hm2 = (s >= 2) ? h[rb - 2 * H] : 0.f;
  float hp1 = (s <= SEQ - 2) ? h[rb + H] : 0.f;
  float hp2 = (s <= SEQ - 3) ? h[rb + 2 * H] : 0.f;
  long cb = (long)row * KC;
  cat[cb + j] = f2b(v);
  cat[cb + H + j] = f2b((hm1 + hm2) * msk);
  cat[cb + 2 * H + j] = f2b((hp1 + hp2) * msk);
}

// =====================================================================
// 256x256 bf16 MFMA GEMM — merged 2-phase/tile schedule.
// Per tile (BK=64, 2 k-halves): only 2 load-bearing barriers:
//   phase-A end (protects phase-B STAGEs overwriting cb k0 regions),
//   tile end after counted vmcnt(4) (next tile resident + nb k1 WAR).
// MFMA accumulation order identical to round-3 kernel (bit-identical).
// =====================================================================
#define MFMA16(AF, BF, MOFF)                                              \
  {                                                                       \
    _Pragma("unroll") for (int mf_ = 0; mf_ < 4; ++mf_)                   \
      _Pragma("unroll") for (int nf_ = 0; nf_ < 4; ++nf_)                 \
        acc[(MOFF) + mf_][nf_] = __builtin_amdgcn_mfma_f32_16x16x32_bf16( \
            AF[mf_], BF[nf_], acc[(MOFF) + mf_][nf_], 0, 0, 0);           \
  }

__global__ __launch_bounds__(512) void gemm256_gate(
    const short* __restrict__ A, int lda,
    const short* __restrict__ BT, int ldb,
    int N, int K, const float* __restrict__ bias,
    float* __restrict__ outF) {
  __shared__ __align__(16) short lds[65536];  // 128 KiB
  const int nbn = N >> 8;
  int bid = blockIdx.x;
  const int nwg = gridDim.x;
  if ((nwg & 7) == 0) {  // bijective XCD swizzle
    const int cpx = nwg >> 3;
    bid = (bid & 7) * cpx + (bid >> 3);
  }
  const int bm = bid / nbn, bn = bid % nbn;
  const int tid = threadIdx.x, lane = tid & 63, wave = tid >> 6;
  const int wm = wave >> 2, wn = wave & 3;
  const int l15 = lane & 15, l4 = lane >> 4;
  const long arow0 = (long)bm * 256, brow0 = (long)bn * 256;
  const int NT = K >> 6;

  f32x4 acc[8][4] = {};

  auto STAGE = [&](int mat, int kh, int tsrc, int sbuf) {
    const short* gb = mat ? BT : A;
    const int ld = mat ? ldb : lda;
    const long r0 = mat ? brow0 : arow0;
    const int kb = tsrc * 64 + kh * 32;
#pragma unroll
    for (int i = 0; i < 2; ++i) {
      const int L16 = i * 512 + tid;          // 16B-granule index in half
      const int r = L16 >> 2;                 // row 0..255
      const int cs = ((L16 & 3) << 4) ^ (((r >> 1) & 3) << 4);  // swz byte col
      gload_lds16(gb + (r0 + r) * ld + kb + (cs >> 1),
                  lds + sbuf * 32768 + mat * 16384 + kh * 8192 +
                      (i * 512 + (wave << 6)) * 8);
    }
  };
  auto LDA4 = [&](int sbuf, int ks, int mh, s16x8* f) {
#pragma unroll
    for (int mf = 0; mf < 4; ++mf) {
      const int r = wm * 128 + mh * 64 + mf * 16 + l15;
      const int c = (l4 << 4) ^ (((r >> 1) & 3) << 4);
      f[mf] = *(const s16x8*)(lds + sbuf * 32768 + ks * 8192 + r * 32 + (c >> 1));
    }
  };
  auto LDB4 = [&](int sbuf, int ks, s16x8* f) {
#pragma unroll
    for (int nf = 0; nf < 4; ++nf) {
      const int r = wn * 64 + nf * 16 + l15;
      const int c = (l4 << 4) ^ (((r >> 1) & 3) << 4);
      f[nf] = *(const s16x8*)(lds + sbuf * 32768 + 16384 + ks * 8192 + r * 32 + (c >> 1));
    }
  };

  // prologue: tile0 (4 halves) + tile1 k0 pair; counted wait
  STAGE(0, 0, 0, 0); STAGE(1, 0, 0, 0); STAGE(0, 1, 0, 0); STAGE(1, 1, 0, 0);
  {
    const int t1p = (NT > 1) ? 1 : 0;
    STAGE(0, 0, t1p, 1); STAGE(1, 0, t1p, 1);
  }
  SFEN();
  asm volatile("s_waitcnt vmcnt(4)" ::: "memory");
  SBAR();
  SFEN();

  for (int t = 0; t < NT; ++t) {
    const int cb = t & 1, nb = cb ^ 1;
    const int t1 = (t + 1 < NT) ? t + 1 : NT - 1;
    const int t2 = (t + 2 < NT) ? t + 2 : NT - 1;
    s16x8 fa[4], fa2[4], fb[4];

    // ---- phase A: k-half 0 (m0 then m1); stage tile t+1 k1 pair -> nb
    LDA4(cb, 0, 0, fa); LDB4(cb, 0, fb);
    STAGE(0, 1, t1, nb); STAGE(1, 1, t1, nb);
    SFEN();
    asm volatile("s_waitcnt lgkmcnt(0)" ::: "memory");
    SFEN();
    __builtin_amdgcn_s_setprio(1);
    MFMA16(fa, fb, 0);
    LDA4(cb, 0, 1, fa2);     // compiler interleaves + inserts lgkm waits
    MFMA16(fa2, fb, 4);
    __builtin_amdgcn_s_setprio(0);
    SFEN(); SBAR(); SFEN();  // all cb-k0 reads complete before overwrite

    // ---- phase B: k-half 1 (m0 then m1); stage tile t+2 k0 pair -> cb
    LDA4(cb, 1, 0, fa); LDB4(cb, 1, fb);
    STAGE(0, 0, t2, cb); STAGE(1, 0, t2, cb);
    SFEN();
    asm volatile("s_waitcnt lgkmcnt(0)" ::: "memory");
    SFEN();
    __builtin_amdgcn_s_setprio(1);
    MFMA16(fa, fb, 0);
    LDA4(cb, 1, 1, fa2);
    MFMA16(fa2, fb, 4);
    __builtin_amdgcn_s_setprio(0);
    SFEN();
    asm volatile("s_waitcnt vmcnt(4)" ::: "memory");  // tile t+1 fully resident
    SBAR();
    SFEN();
  }
  asm volatile("s_waitcnt vmcnt(0)" ::: "memory");

  // epilogue: C = acc + bias
#pragma unroll
  for (int mi = 0; mi < 8; ++mi) {
#pragma unroll
    for (int nf = 0; nf < 4; ++nf) {
#pragma unroll
      for (int j = 0; j < 4; ++j) {
        const long row = arow0 + wm * 128 + mi * 16 + l4 * 4 + j;
        const long col = brow0 + wn * 64 + nf * 16 + l15;
        outF[row * N + col] = acc[mi][nf][j] + bias[col];
      }
    }
  }
}

// ---------------- 128x128 bf16 MFMA GEMM (small GEMMs), proven
// EPI 0: emb  = bf16(tanh(acc + bias[col]))
// EPI 2: t1   = bf16(relu(acc + bias[col]))
// EPI 3: out  = acc + bias[col] + addF[row*N+col]     (f32)
template <int EPI>
__global__ __launch_bounds__(256) void gemm_bt(
    const short* __restrict__ A, int lda, const short* __restrict__ BT,
    int M, int N, int K,
    const float* __restrict__ bias,
    const float* __restrict__ addF,
    float* __restrict__ outF, short* __restrict__ outB) {
  __shared__ __align__(16) short As[128 * 32];
  __shared__ __align__(16) short Bs[128 * 32];
  const int nbn = N >> 7;
  const int bm = blockIdx.x / nbn;
  const int bn = blockIdx.x % nbn;
  const int tid = threadIdx.x;
  const int lane = tid & 63;
  const int wave = tid >> 6;
  const int wr = (wave >> 1) << 6;
  const int wc = (wave & 1) << 6;
  const int l15 = lane & 15;
  const int krow = (lane >> 4) << 3;

  f32x4 acc[4][4] = {};

  const long arow0 = (long)bm * 128;
  const long brow0 = (long)bn * 128;

  for (int k0 = 0; k0 < K; k0 += 32) {
#pragma unroll
    for (int i = 0; i < 2; ++i) {
      const int e = (i * 256 + tid) * 8;
      const int r = e >> 5, c = e & 31;
      gload_lds16(A + (arow0 + r) * lda + k0 + c, As + (long)(i * 256 + (wave << 6)) * 8);
      gload_lds16(BT + (brow0 + r) * K + k0 + c, Bs + (long)(i * 256 + (wave << 6)) * 8);
    }
    __syncthreads();
    s16x8 af[4], bfr[4];
#pragma unroll
    for (int m = 0; m < 4; ++m)
      af[m] = *(const s16x8*)(As + (wr + m * 16 + l15) * 32 + krow);
#pragma unroll
    for (int n = 0; n < 4; ++n)
      bfr[n] = *(const s16x8*)(Bs + (wc + n * 16 + l15) * 32 + krow);
#pragma unroll
    for (int m = 0; m < 4; ++m)
#pragma unroll
      for (int n = 0; n < 4; ++n)
        acc[m][n] = __builtin_amdgcn_mfma_f32_16x16x32_bf16(af[m], bfr[n], acc[m][n], 0, 0, 0);
    __syncthreads();
  }

#pragma unroll
  for (int m = 0; m < 4; ++m) {
#pragma unroll
    for (int n = 0; n < 4; ++n) {
#pragma unroll
      for (int j = 0; j < 4; ++j) {
        const long row = arow0 + wr + m * 16 + ((lane >> 4) << 2) + j;
        const long col = brow0 + wc + n * 16 + l15;
        const float v = acc[m][n][j];
        if (EPI == 0) {
          outB[row * N + col] = f2b(tanhf(v + bias[col]));
        } else if (EPI == 2) {
          outB[row * N + col] = f2b(fmaxf(v + bias[col], 0.f));
        } else {
          outF[row * N + col] = v + bias[col] + addF[row * N + col];
        }
      }
    }
  }
}

// ---------------- per-row pointwise: 6 LayerNorms + gates + cell update
__global__ __launch_bounds__(512) void pointwise(
    const float* __restrict__ gates, const short* __restrict__ emb,
    const float* __restrict__ cin, float* __restrict__ cout,
    float* __restrict__ h, const int* __restrict__ mask,
    const float* __restrict__ lng, const float* __restrict__ lnb, int row0) {
  const int row = row0 + blockIdx.x;
  const int s = row & (SEQ - 1);
  const int tid = threadIdx.x;
  const int lane = tid & 63, wave = tid >> 6;
  const float msk = mask[row] ? 0.f : 1.f;
  const float* grow = gates + (long)blockIdx.x * G7;

  float g[7];
#pragma unroll
  for (int k = 0; k < 7; ++k) g[k] = grow[k * H + tid];

  const int cidx[6] = {0, 1, 2, 3, 4, 6};
  float red[12];
#pragma unroll
  for (int i = 0; i < 6; ++i) {
    float v = g[cidx[i]];
    red[i] = v; red[6 + i] = v * v;
  }
#pragma unroll
  for (int st = 32; st > 0; st >>= 1) {
#pragma unroll
    for (int i = 0; i < 12; ++i) red[i] += __shfl_xor(red[i], st, 64);
  }
  __shared__ float lred[8][12];
  __shared__ float fin[12];
  if (lane == 0) {
#pragma unroll
    for (int i = 0; i < 12; ++i) lred[wave][i] = red[i];
  }
  __syncthreads();
  if (tid < 12) {
    float a = 0.f;
#pragma unroll
    for (int w = 0; w < 8; ++w) a += lred[w][tid];
    fin[tid] = a;
  }
  __syncthreads();

  float ln[6];
#pragma unroll
  for (int i = 0; i < 6; ++i) {
    float mean = fin[i] * (1.f / (float)H);
    float var = fin[6 + i] * (1.f / (float)H) - mean * mean;
    float inv = rsqrtf(var + LNEPS);
    int pidx = (i < 5) ? i : 5;
    ln[i] = (g[cidx[i]] - mean) * inv * lng[pidx * H + tid] + lnb[pidx * H + tid];
  }
  float gfl = ln[0], gfr = ln[1], gfc = ln[2];
  float gi = 1.f / (1.f + expf(-ln[3]));
  float ge = 1.f / (1.f + expf(-ln[4]));
  float go = 1.f / (1.f + expf(-ln[5]));
  float gw = tanhf(g[5]) + ge * b2f(emb[(long)row * H + tid]);

  float mx = fmaxf(gfl, fmaxf(gfr, gfc));
  float e0 = expf(gfl - mx), e1 = expf(gfr - mx), e2 = expf(gfc - mx);
  float inv3 = 1.f / (e0 + e1 + e2);
  float f0 = e0 * inv3, f1 = e1 * inv3, f2 = e2 * inv3;

  const long rb = (long)row * H + tid;
  float cc = cin[rb];
  float cm1 = (s >= 1) ? cin[rb - H] : 0.f;
  float cm2 = (s >= 2) ? cin[rb - 2 * H] : 0.f;
  float cp1 = (s <= SEQ - 2) ? cin[rb + H] : 0.f;
  float cp2 = (s <= SEQ - 3) ? cin[rb + 2 * H] : 0.f;
  float cbv = (cm1 + cm2) * msk, cav = (cp1 + cp2) * msk;
  float lc = cbv * f0 + cav * f1 + cc * f2;
  float cn = (lc * (1.f - gi) + gw * gi) * msk;
  float hv = go * tanhf(cn) * msk;
  cout[rb] = cn;
  h[rb] = hv;
}

// ---------------- final LN over h -> hn (f32 + bf16)
__global__ __launch_bounds__(512) void ln_final(
    const float* __restrict__ h, const float* __restrict__ g6,
    const float* __restrict__ b6, float* __restrict__ hnF,
    short* __restrict__ hnB) {
  const int row = blockIdx.x;
  const int tid = threadIdx.x;
  const int lane = tid & 63, wave = tid >> 6;
  const long rb = (long)row * H + tid;
  float v = h[rb];
  float r0 = v, r1 = v * v;
#pragma unroll
  for (int st = 32; st > 0; st >>= 1) {
    r0 += __shfl_xor(r0, st, 64);
    r1 += __shfl_xor(r1, st, 64);
  }
  __shared__ float lred[8][2];
  __shared__ float fin[2];
  if (lane == 0) { lred[wave][0] = r0; lred[wave][1] = r1; }
  __syncthreads();
  if (tid < 2) {
    float a = 0.f;
#pragma unroll
    for (int w = 0; w < 8; ++w) a += lred[w][tid];
    fin[tid] = a;
  }
  __syncthreads();
  float mean = fin[0] * (1.f / (float)H);
  float var = fin[1] * (1.f / (float)H) - mean * mean;
  float inv = rsqrtf(var + LNEPS);
  float o = (v - mean) * inv * g6[tid] + b6[tid];
  hnF[rb] = o;
  hnB[rb] = f2b(o);
}

extern "C" void kernel_launch(void* const* d_in, const int* in_sizes, int n_in,
                              void* d_out, int out_size, void* d_ws, size_t ws_size,
                              hipStream_t stream) {
  const float* word = (const float*)d_in[0];
  const int* mask = (const int*)d_in[1];
  const float* Wg = (const float*)d_in[2];
  const float* bg = (const float*)d_in[3];
  const float* We_gate = (const float*)d_in[4];
  const float* We_trans = (const float*)d_in[5];
  const float* be_trans = (const float*)d_in[6];
  const float* W1 = (const float*)d_in[7];
  const float* b1 = (const float*)d_in[8];
  const float* W2 = (const float*)d_in[9];
  const float* b2 = (const float*)d_in[10];
  const float* ln_g = (const float*)d_in[11];
  const float* ln_b = (const float*)d_in[12];
  float* out = (float*)d_out;

  // single-chunk (M=8192) needs ~227 MB of ws; else fall back to 2x4096.
  // ws_size is constant across calls, so this branch is deterministic.
  const int mchunk = (ws_size >= (size_t)228 * 1024 * 1024) ? ROWS : ROWS / 2;

  char* p = (char*)d_ws;
  auto take = [&](size_t bytes) -> char* {
    char* r = p;
    p += (bytes + 255) & ~(size_t)255;
    return r;
  };
  short* WgT   = (short*)take((size_t)G7 * KC * 2);        // 14.7 MB
  short* WeTt  = (short*)take((size_t)H * H * 2);          // 0.5 MB
  short* W1T   = (short*)take((size_t)(2 * H) * H * 2);    // 1 MB
  short* W2T   = (short*)take((size_t)H * (2 * H) * 2);    // 1 MB
  short* cat   = (short*)take((size_t)ROWS * KC * 2);      // 32 MB
  float* gates = (float*)take((size_t)mchunk * G7 * 4);    // 56 or 112 MB
  short* emb   = (short*)take((size_t)ROWS * H * 2);       // 8 MB
  float* h     = (float*)take((size_t)ROWS * H * 4);       // 16 MB
  float* c0    = (float*)take((size_t)ROWS * H * 4);       // 16 MB
  float* c1    = (float*)take((size_t)ROWS * H * 4);       // 16 MB
  // post-loop aliases (regions dead after layer loop):
  float* hnF = c0;
  short* hnB = emb;
  short* t1  = (short*)gates;

  trans_fused<<<8448, 256, 0, stream>>>(Wg, We_gate, We_trans, W1, W2,
                                        WgT, WeTt, W1T, W2T);

  prep<<<ROWS * H / 256, 256, 0, stream>>>(word, mask, h, c0, cat);

  // emb = bf16(tanh(x @ We_trans + be)) ; A = x-part of cat (lda=KC)
  gemm_bt<0><<<(ROWS / 128) * (H / 128), 256, 0, stream>>>(
      cat + K3, KC, WeTt, ROWS, H, H, be_trans, nullptr, nullptr, emb);

  float* cin = c0;
  float* cout = c1;
  for (int l = 0; l < NLAYERS; ++l) {
    build_cat<<<ROWS, 512, 0, stream>>>(h, mask, cat);
    for (int ch = 0; ch < ROWS / mchunk; ++ch) {
      gemm256_gate<<<(mchunk / 256) * (G7 / 256), 512, 0, stream>>>(
          cat + (long)ch * mchunk * KC, KC, WgT, KC, G7, KC, bg, gates);
      pointwise<<<mchunk, 512, 0, stream>>>(gates, emb, cin, cout, h, mask,
                                            ln_g, ln_b, ch * mchunk);
    }
    float* tmp = cin; cin = cout; cout = tmp;
  }

  ln_final<<<ROWS, 512, 0, stream>>>(h, ln_g + 6 * H, ln_b + 6 * H, hnF, hnB);
  gemm_bt<2><<<(ROWS / 128) * ((2 * H) / 128), 256, 0, stream>>>(
      hnB, H, W1T, ROWS, 2 * H, H, b1, nullptr, nullptr, t1);
  gemm_bt<3><<<(ROWS / 128) * (H / 128), 256, 0, stream>>>(
      t1, 2 * H, W2T, ROWS, H, 2 * H, b2, hnF, out, nullptr);
}

// Round 7
// 1406.145 us; speedup vs baseline: 1.6527x; 1.1452x over previous
//
#include <hip/hip_runtime.h>

#define H 512
#define SEQ 256
#define BATCH 32
#define ROWS (BATCH * SEQ)   // 8192
#define G7 (7 * H)           // 3584
#define K3 (3 * H)           // 1536
#define KC 2048              // cat width: [h, hb, ha, x]
#define NLAYERS 7
#define LNEPS 1e-5f

typedef __attribute__((ext_vector_type(8))) short s16x8;
typedef __attribute__((ext_vector_type(4))) short s16x4;
typedef __attribute__((ext_vector_type(4))) float f32x4;

__device__ __forceinline__ short f2b(float f) {
  union { float f; unsigned u; } x; x.f = f;
  unsigned r = x.u + 0x7fffu + ((x.u >> 16) & 1u);
  return (short)(r >> 16);
}
__device__ __forceinline__ float b2f(short s) {
  union { unsigned u; float f; } x; x.u = ((unsigned)(unsigned short)s) << 16;
  return x.f;
}
__device__ __forceinline__ s16x4 f2b4(f32x4 v) {
  s16x4 r; r.x = f2b(v.x); r.y = f2b(v.y); r.z = f2b(v.z); r.w = f2b(v.w);
  return r;
}

__device__ __forceinline__ void gload_lds16(const void* g, void* l) {
  __builtin_amdgcn_global_load_lds(
      (const __attribute__((address_space(1))) void*)g,
      (__attribute__((address_space(3))) void*)l, 16, 0, 0);
}

#define SFEN() __builtin_amdgcn_sched_barrier(0)
#define SBAR() __builtin_amdgcn_s_barrier()

// ---------------- fused weight transposes (one dispatch)
// block ranges: [0,7168) WgT ; [7168,7424) WeTt ; [7424,7936) W1T ; [7936,8448) W2T
__global__ __launch_bounds__(256) void trans_fused(
    const float* __restrict__ Wg, const float* __restrict__ Weg,
    const float* __restrict__ Wet, const float* __restrict__ W1,
    const float* __restrict__ W2,
    short* __restrict__ WgT, short* __restrict__ WeTt,
    short* __restrict__ W1T, short* __restrict__ W2T) {
  __shared__ float t[32][33];
  int b = blockIdx.x;
  const float *s1, *s2; short* o; int Kd, Nd, bound;
  if (b < 7168)      { s1 = Wg;  s2 = Weg; o = WgT;  Kd = KC;   Nd = G7;   bound = K3; }
  else if (b < 7424) { b -= 7168; s1 = s2 = Wet; o = WeTt; Kd = 512;  Nd = 512;  bound = 1 << 30; }
  else if (b < 7936) { b -= 7424; s1 = s2 = W1;  o = W1T;  Kd = 512;  Nd = 1024; bound = 1 << 30; }
  else               { b -= 7936; s1 = s2 = W2;  o = W2T;  Kd = 1024; Nd = 512;  bound = 1 << 30; }
  const int nbn = Nd / 32;
  const int bn = b % nbn, bk = b / nbn;
  const int n0 = bn * 32, k0 = bk * 32;
  const int tx = threadIdx.x & 31, ty = threadIdx.x >> 5;  // ty 0..7
#pragma unroll
  for (int i = 0; i < 4; ++i) {
    const int k = k0 + ty + i * 8;
    t[ty + i * 8][tx] = (k < bound) ? s1[(long)k * Nd + n0 + tx]
                                    : s2[(long)(k - K3) * Nd + n0 + tx];
  }
  __syncthreads();
#pragma unroll
  for (int i = 0; i < 4; ++i) {
    const int n = ty + i * 8;
    o[(long)(n0 + n) * Kd + k0 + tx] = f2b(t[tx][n]);
  }
}

// ---------------- prep: x = word*mask ; h = c0 = x (f32) ; cat x-part = bf16(x)
__global__ void prep(const float* __restrict__ word, const int* __restrict__ mask,
                     float* __restrict__ h, float* __restrict__ c0,
                     short* __restrict__ cat) {
  long i = (long)blockIdx.x * 256 + threadIdx.x;
  int row = (int)(i >> 9);
  int j = (int)(i & (H - 1));
  float msk = mask[row] ? 0.f : 1.f;
  float v = word[i] * msk;
  h[i] = v; c0[i] = v;
  cat[(long)row * KC + K3 + j] = f2b(v);
}

// ---------------- per layer: cat[:, 0:1536) = [h, hb, ha] bf16
// 4 rows/block, 128 threads/row, float4 loads + short4 stores (G13)
__global__ __launch_bounds__(512) void build_cat4(const float* __restrict__ h,
                                                  const int* __restrict__ mask,
                                                  short* __restrict__ cat) {
  const int tid = threadIdx.x;
  const int rloc = tid >> 7, jj = tid & 127;
  const int row = (blockIdx.x << 2) + rloc;
  const int s = row & (SEQ - 1);
  const float msk = mask[row] ? 0.f : 1.f;
  const long rb = (long)row * H + jj * 4;
  const f32x4 z = {0.f, 0.f, 0.f, 0.f};
  f32x4 v = *(const f32x4*)(h + rb);
  f32x4 hm1 = (s >= 1) ? *(const f32x4*)(h + rb - H) : z;
  f32x4 hm2 = (s >= 2) ? *(const f32x4*)(h + rb - 2 * H) : z;
  f32x4 hp1 = (s <= SEQ - 2) ? *(const f32x4*)(h + rb + H) : z;
  f32x4 hp2 = (s <= SEQ - 3) ? *(const f32x4*)(h + rb + 2 * H) : z;
  const long cb = (long)row * KC + jj * 4;
  *(s16x4*)(cat + cb) = f2b4(v);
  *(s16x4*)(cat + cb + H) = f2b4((hm1 + hm2) * msk);
  *(s16x4*)(cat + cb + 2 * H) = f2b4((hp1 + hp2) * msk);
}

// =====================================================================
// 256x256 bf16 MFMA GEMM — merged 2-phase/tile schedule (proven r6).
// =====================================================================
#define MFMA16(AF, BF, MOFF)                                              \
  {                                                                       \
    _Pragma("unroll") for (int mf_ = 0; mf_ < 4; ++mf_)                   \
      _Pragma("unroll") for (int nf_ = 0; nf_ < 4; ++nf_)                 \
        acc[(MOFF) + mf_][nf_] = __builtin_amdgcn_mfma_f32_16x16x32_bf16( \
            AF[mf_], BF[nf_], acc[(MOFF) + mf_][nf_], 0, 0, 0);           \
  }

__global__ __launch_bounds__(512) void gemm256_gate(
    const short* __restrict__ A, int lda,
    const short* __restrict__ BT, int ldb,
    int N, int K, const float* __restrict__ bias,
    float* __restrict__ outF) {
  __shared__ __align__(16) short lds[65536];  // 128 KiB
  const int nbn = N >> 8;
  int bid = blockIdx.x;
  const int nwg = gridDim.x;
  if ((nwg & 7) == 0) {  // bijective XCD swizzle
    const int cpx = nwg >> 3;
    bid = (bid & 7) * cpx + (bid >> 3);
  }
  const int bm = bid / nbn, bn = bid % nbn;
  const int tid = threadIdx.x, lane = tid & 63, wave = tid >> 6;
  const int wm = wave >> 2, wn = wave & 3;
  const int l15 = lane & 15, l4 = lane >> 4;
  const long arow0 = (long)bm * 256, brow0 = (long)bn * 256;
  const int NT = K >> 6;

  f32x4 acc[8][4] = {};

  auto STAGE = [&](int mat, int kh, int tsrc, int sbuf) {
    const short* gb = mat ? BT : A;
    const int ld = mat ? ldb : lda;
    const long r0 = mat ? brow0 : arow0;
    const int kb = tsrc * 64 + kh * 32;
#pragma unroll
    for (int i = 0; i < 2; ++i) {
      const int L16 = i * 512 + tid;          // 16B-granule index in half
      const int r = L16 >> 2;                 // row 0..255
      const int cs = ((L16 & 3) << 4) ^ (((r >> 1) & 3) << 4);  // swz byte col
      gload_lds16(gb + (r0 + r) * ld + kb + (cs >> 1),
                  lds + sbuf * 32768 + mat * 16384 + kh * 8192 +
                      (i * 512 + (wave << 6)) * 8);
    }
  };
  auto LDA4 = [&](int sbuf, int ks, int mh, s16x8* f) {
#pragma unroll
    for (int mf = 0; mf < 4; ++mf) {
      const int r = wm * 128 + mh * 64 + mf * 16 + l15;
      const int c = (l4 << 4) ^ (((r >> 1) & 3) << 4);
      f[mf] = *(const s16x8*)(lds + sbuf * 32768 + ks * 8192 + r * 32 + (c >> 1));
    }
  };
  auto LDB4 = [&](int sbuf, int ks, s16x8* f) {
#pragma unroll
    for (int nf = 0; nf < 4; ++nf) {
      const int r = wn * 64 + nf * 16 + l15;
      const int c = (l4 << 4) ^ (((r >> 1) & 3) << 4);
      f[nf] = *(const s16x8*)(lds + sbuf * 32768 + 16384 + ks * 8192 + r * 32 + (c >> 1));
    }
  };

  // prologue: tile0 (4 halves) + tile1 k0 pair; counted wait
  STAGE(0, 0, 0, 0); STAGE(1, 0, 0, 0); STAGE(0, 1, 0, 0); STAGE(1, 1, 0, 0);
  {
    const int t1p = (NT > 1) ? 1 : 0;
    STAGE(0, 0, t1p, 1); STAGE(1, 0, t1p, 1);
  }
  SFEN();
  asm volatile("s_waitcnt vmcnt(4)" ::: "memory");
  SBAR();
  SFEN();

  for (int t = 0; t < NT; ++t) {
    const int cb = t & 1, nb = cb ^ 1;
    const int t1 = (t + 1 < NT) ? t + 1 : NT - 1;
    const int t2 = (t + 2 < NT) ? t + 2 : NT - 1;
    s16x8 fa[4], fa2[4], fb[4];

    // ---- phase A: k-half 0 (m0 then m1); stage tile t+1 k1 pair -> nb
    LDA4(cb, 0, 0, fa); LDB4(cb, 0, fb);
    STAGE(0, 1, t1, nb); STAGE(1, 1, t1, nb);
    SFEN();
    asm volatile("s_waitcnt lgkmcnt(0)" ::: "memory");
    SFEN();
    __builtin_amdgcn_s_setprio(1);
    MFMA16(fa, fb, 0);
    LDA4(cb, 0, 1, fa2);     // compiler interleaves + inserts lgkm waits
    MFMA16(fa2, fb, 4);
    __builtin_amdgcn_s_setprio(0);
    SFEN(); SBAR(); SFEN();  // all cb-k0 reads complete before overwrite

    // ---- phase B: k-half 1 (m0 then m1); stage tile t+2 k0 pair -> cb
    LDA4(cb, 1, 0, fa); LDB4(cb, 1, fb);
    STAGE(0, 0, t2, cb); STAGE(1, 0, t2, cb);
    SFEN();
    asm volatile("s_waitcnt lgkmcnt(0)" ::: "memory");
    SFEN();
    __builtin_amdgcn_s_setprio(1);
    MFMA16(fa, fb, 0);
    LDA4(cb, 1, 1, fa2);
    MFMA16(fa2, fb, 4);
    __builtin_amdgcn_s_setprio(0);
    SFEN();
    asm volatile("s_waitcnt vmcnt(4)" ::: "memory");  // tile t+1 fully resident
    SBAR();
    SFEN();
  }
  asm volatile("s_waitcnt vmcnt(0)" ::: "memory");

  // epilogue: C = acc + bias
#pragma unroll
  for (int mi = 0; mi < 8; ++mi) {
#pragma unroll
    for (int nf = 0; nf < 4; ++nf) {
#pragma unroll
      for (int j = 0; j < 4; ++j) {
        const long row = arow0 + wm * 128 + mi * 16 + l4 * 4 + j;
        const long col = brow0 + wn * 64 + nf * 16 + l15;
        outF[row * N + col] = acc[mi][nf][j] + bias[col];
      }
    }
  }
}

// ---------------- 128x128 bf16 MFMA GEMM (small GEMMs), proven
// EPI 0: emb  = bf16(tanh(acc + bias[col]))
// EPI 2: t1   = bf16(relu(acc + bias[col]))
// EPI 3: out  = acc + bias[col] + addF[row*N+col]     (f32)
template <int EPI>
__global__ __launch_bounds__(256) void gemm_bt(
    const short* __restrict__ A, int lda, const short* __restrict__ BT,
    int M, int N, int K,
    const float* __restrict__ bias,
    const float* __restrict__ addF,
    float* __restrict__ outF, short* __restrict__ outB) {
  __shared__ __align__(16) short As[128 * 32];
  __shared__ __align__(16) short Bs[128 * 32];
  const int nbn = N >> 7;
  const int bm = blockIdx.x / nbn;
  const int bn = blockIdx.x % nbn;
  const int tid = threadIdx.x;
  const int lane = tid & 63;
  const int wave = tid >> 6;
  const int wr = (wave >> 1) << 6;
  const int wc = (wave & 1) << 6;
  const int l15 = lane & 15;
  const int krow = (lane >> 4) << 3;

  f32x4 acc[4][4] = {};

  const long arow0 = (long)bm * 128;
  const long brow0 = (long)bn * 128;

  for (int k0 = 0; k0 < K; k0 += 32) {
#pragma unroll
    for (int i = 0; i < 2; ++i) {
      const int e = (i * 256 + tid) * 8;
      const int r = e >> 5, c = e & 31;
      gload_lds16(A + (arow0 + r) * lda + k0 + c, As + (long)(i * 256 + (wave << 6)) * 8);
      gload_lds16(BT + (brow0 + r) * K + k0 + c, Bs + (long)(i * 256 + (wave << 6)) * 8);
    }
    __syncthreads();
    s16x8 af[4], bfr[4];
#pragma unroll
    for (int m = 0; m < 4; ++m)
      af[m] = *(const s16x8*)(As + (wr + m * 16 + l15) * 32 + krow);
#pragma unroll
    for (int n = 0; n < 4; ++n)
      bfr[n] = *(const s16x8*)(Bs + (wc + n * 16 + l15) * 32 + krow);
#pragma unroll
    for (int m = 0; m < 4; ++m)
#pragma unroll
      for (int n = 0; n < 4; ++n)
        acc[m][n] = __builtin_amdgcn_mfma_f32_16x16x32_bf16(af[m], bfr[n], acc[m][n], 0, 0, 0);
    __syncthreads();
  }

#pragma unroll
  for (int m = 0; m < 4; ++m) {
#pragma unroll
    for (int n = 0; n < 4; ++n) {
#pragma unroll
      for (int j = 0; j < 4; ++j) {
        const long row = arow0 + wr + m * 16 + ((lane >> 4) << 2) + j;
        const long col = brow0 + wc + n * 16 + l15;
        const float v = acc[m][n][j];
        if (EPI == 0) {
          outB[row * N + col] = f2b(tanhf(v + bias[col]));
        } else if (EPI == 2) {
          outB[row * N + col] = f2b(fmaxf(v + bias[col], 0.f));
        } else {
          outF[row * N + col] = v + bias[col] + addF[row * N + col];
        }
      }
    }
  }
}

// ---------------- per-row pointwise, vectorized: 4 rows/block, 128 thr/row,
// float4 (16B/lane) loads/stores. LN stats: per-wave shuffle (64 lanes of a
// wave all belong to one row) + one LDS combine of the 2 waves per row.
__global__ __launch_bounds__(512) void pointwise4(
    const float* __restrict__ gates, const short* __restrict__ emb,
    const float* __restrict__ cin, float* __restrict__ cout,
    float* __restrict__ h, const int* __restrict__ mask,
    const float* __restrict__ lng, const float* __restrict__ lnb, int row0) {
  const int tid = threadIdx.x;
  const int rloc = tid >> 7;            // 0..3 row within block
  const int jj = tid & 127;             // col-group (4 cols each)
  const int lane = tid & 63, wave = tid >> 6;
  const int lrow = (blockIdx.x << 2) + rloc;   // local row in gates chunk
  const int row = row0 + lrow;
  const int s = row & (SEQ - 1);
  const float msk = mask[row] ? 0.f : 1.f;
  const float* grow = gates + (long)lrow * G7 + jj * 4;

  f32x4 g[7];
#pragma unroll
  for (int k = 0; k < 7; ++k) g[k] = *(const f32x4*)(grow + k * H);

  const int cidx[6] = {0, 1, 2, 3, 4, 6};
  float red[12];
#pragma unroll
  for (int i = 0; i < 6; ++i) {
    f32x4 v = g[cidx[i]];
    red[i] = v.x + v.y + v.z + v.w;
    red[6 + i] = v.x * v.x + v.y * v.y + v.z * v.z + v.w * v.w;
  }
#pragma unroll
  for (int st = 32; st > 0; st >>= 1) {
#pragma unroll
    for (int i = 0; i < 12; ++i) red[i] += __shfl_xor(red[i], st, 64);
  }
  __shared__ float lred[8][12];
  if (lane == 0) {
#pragma unroll
    for (int i = 0; i < 12; ++i) lred[wave][i] = red[i];
  }
  __syncthreads();

  f32x4 ln[6];
#pragma unroll
  for (int i = 0; i < 6; ++i) {
    const float sum = lred[rloc * 2][i] + lred[rloc * 2 + 1][i];
    const float sq = lred[rloc * 2][6 + i] + lred[rloc * 2 + 1][6 + i];
    const float mean = sum * (1.f / (float)H);
    const float var = sq * (1.f / (float)H) - mean * mean;
    const float inv = rsqrtf(var + LNEPS);
    const int pidx = (i < 5) ? i : 5;
    const f32x4 ga = *(const f32x4*)(lng + pidx * H + jj * 4);
    const f32x4 be = *(const f32x4*)(lnb + pidx * H + jj * 4);
    ln[i] = (g[cidx[i]] - mean) * inv * ga + be;
  }

  const long rb = (long)row * H + jj * 4;
  const s16x4 e4 = *(const s16x4*)(emb + rb);
  f32x4 emb4; emb4.x = b2f(e4.x); emb4.y = b2f(e4.y); emb4.z = b2f(e4.z); emb4.w = b2f(e4.w);

  f32x4 gi, ge, go, gw, f0, f1, f2;
#pragma unroll
  for (int q = 0; q < 4; ++q) {
    gi[q] = 1.f / (1.f + expf(-ln[3][q]));
    ge[q] = 1.f / (1.f + expf(-ln[4][q]));
    go[q] = 1.f / (1.f + expf(-ln[5][q]));
    gw[q] = tanhf(g[5][q]) + ge[q] * emb4[q];
    const float mx = fmaxf(ln[0][q], fmaxf(ln[1][q], ln[2][q]));
    const float e0 = expf(ln[0][q] - mx);
    const float e1 = expf(ln[1][q] - mx);
    const float e2 = expf(ln[2][q] - mx);
    const float inv3 = 1.f / (e0 + e1 + e2);
    f0[q] = e0 * inv3; f1[q] = e1 * inv3; f2[q] = e2 * inv3;
  }

  const f32x4 z = {0.f, 0.f, 0.f, 0.f};
  const f32x4 cc = *(const f32x4*)(cin + rb);
  const f32x4 cm1 = (s >= 1) ? *(const f32x4*)(cin + rb - H) : z;
  const f32x4 cm2 = (s >= 2) ? *(const f32x4*)(cin + rb - 2 * H) : z;
  const f32x4 cp1 = (s <= SEQ - 2) ? *(const f32x4*)(cin + rb + H) : z;
  const f32x4 cp2 = (s <= SEQ - 3) ? *(const f32x4*)(cin + rb + 2 * H) : z;
  const f32x4 cbv = (cm1 + cm2) * msk;
  const f32x4 cav = (cp1 + cp2) * msk;
  const f32x4 lc = cbv * f0 + cav * f1 + cc * f2;
  f32x4 cn = (lc * (1.f - gi) + gw * gi) * msk;
  f32x4 hv;
#pragma unroll
  for (int q = 0; q < 4; ++q) hv[q] = go[q] * tanhf(cn[q]) * msk;
  *(f32x4*)(cout + rb) = cn;
  *(f32x4*)(h + rb) = hv;
}

// ---------------- final LN over h -> hn (f32 + bf16)
__global__ __launch_bounds__(512) void ln_final(
    const float* __restrict__ h, const float* __restrict__ g6,
    const float* __restrict__ b6, float* __restrict__ hnF,
    short* __restrict__ hnB) {
  const int row = blockIdx.x;
  const int tid = threadIdx.x;
  const int lane = tid & 63, wave = tid >> 6;
  const long rb = (long)row * H + tid;
  float v = h[rb];
  float r0 = v, r1 = v * v;
#pragma unroll
  for (int st = 32; st > 0; st >>= 1) {
    r0 += __shfl_xor(r0, st, 64);
    r1 += __shfl_xor(r1, st, 64);
  }
  __shared__ float lred[8][2];
  __shared__ float fin[2];
  if (lane == 0) { lred[wave][0] = r0; lred[wave][1] = r1; }
  __syncthreads();
  if (tid < 2) {
    float a = 0.f;
#pragma unroll
    for (int w = 0; w < 8; ++w) a += lred[w][tid];
    fin[tid] = a;
  }
  __syncthreads();
  float mean = fin[0] * (1.f / (float)H);
  float var = fin[1] * (1.f / (float)H) - mean * mean;
  float inv = rsqrtf(var + LNEPS);
  float o = (v - mean) * inv * g6[tid] + b6[tid];
  hnF[rb] = o;
  hnB[rb] = f2b(o);
}

extern "C" void kernel_launch(void* const* d_in, const int* in_sizes, int n_in,
                              void* d_out, int out_size, void* d_ws, size_t ws_size,
                              hipStream_t stream) {
  const float* word = (const float*)d_in[0];
  const int* mask = (const int*)d_in[1];
  const float* Wg = (const float*)d_in[2];
  const float* bg = (const float*)d_in[3];
  const float* We_gate = (const float*)d_in[4];
  const float* We_trans = (const float*)d_in[5];
  const float* be_trans = (const float*)d_in[6];
  const float* W1 = (const float*)d_in[7];
  const float* b1 = (const float*)d_in[8];
  const float* W2 = (const float*)d_in[9];
  const float* b2 = (const float*)d_in[10];
  const float* ln_g = (const float*)d_in[11];
  const float* ln_b = (const float*)d_in[12];
  float* out = (float*)d_out;

  // single-chunk (M=8192) needs ~227 MB of ws; else fall back to 2x4096.
  // ws_size is constant across calls, so this branch is deterministic.
  const int mchunk = (ws_size >= (size_t)228 * 1024 * 1024) ? ROWS : ROWS / 2;

  char* p = (char*)d_ws;
  auto take = [&](size_t bytes) -> char* {
    char* r = p;
    p += (bytes + 255) & ~(size_t)255;
    return r;
  };
  short* WgT   = (short*)take((size_t)G7 * KC * 2);        // 14.7 MB
  short* WeTt  = (short*)take((size_t)H * H * 2);          // 0.5 MB
  short* W1T   = (short*)take((size_t)(2 * H) * H * 2);    // 1 MB
  short* W2T   = (short*)take((size_t)H * (2 * H) * 2);    // 1 MB
  short* cat   = (short*)take((size_t)ROWS * KC * 2);      // 32 MB
  float* gates = (float*)take((size_t)mchunk * G7 * 4);    // 56 or 112 MB
  short* emb   = (short*)take((size_t)ROWS * H * 2);       // 8 MB
  float* h     = (float*)take((size_t)ROWS * H * 4);       // 16 MB
  float* c0    = (float*)take((size_t)ROWS * H * 4);       // 16 MB
  float* c1    = (float*)take((size_t)ROWS * H * 4);       // 16 MB
  // post-loop aliases (regions dead after layer loop):
  float* hnF = c0;
  short* hnB = emb;
  short* t1  = (short*)gates;

  trans_fused<<<8448, 256, 0, stream>>>(Wg, We_gate, We_trans, W1, W2,
                                        WgT, WeTt, W1T, W2T);

  prep<<<ROWS * H / 256, 256, 0, stream>>>(word, mask, h, c0, cat);

  // emb = bf16(tanh(x @ We_trans + be)) ; A = x-part of cat (lda=KC)
  gemm_bt<0><<<(ROWS / 128) * (H / 128), 256, 0, stream>>>(
      cat + K3, KC, WeTt, ROWS, H, H, be_trans, nullptr, nullptr, emb);

  float* cin = c0;
  float* cout = c1;
  for (int l = 0; l < NLAYERS; ++l) {
    build_cat4<<<ROWS / 4, 512, 0, stream>>>(h, mask, cat);
    for (int ch = 0; ch < ROWS / mchunk; ++ch) {
      gemm256_gate<<<(mchunk / 256) * (G7 / 256), 512, 0, stream>>>(
          cat + (long)ch * mchunk * KC, KC, WgT, KC, G7, KC, bg, gates);
      pointwise4<<<mchunk / 4, 512, 0, stream>>>(gates, emb, cin, cout, h, mask,
                                                 ln_g, ln_b, ch * mchunk);
    }
    float* tmp = cin; cin = cout; cout = tmp;
  }

  ln_final<<<ROWS, 512, 0, stream>>>(h, ln_g + 6 * H, ln_b + 6 * H, hnF, hnB);
  gemm_bt<2><<<(ROWS / 128) * ((2 * H) / 128), 256, 0, stream>>>(
      hnB, H, W1T, ROWS, 2 * H, H, b1, nullptr, nullptr, t1);
  gemm_bt<3><<<(ROWS / 128) * (H / 128), 256, 0, stream>>>(
      t1, 2 * H, W2T, ROWS, H, 2 * H, b2, hnF, out, nullptr);
}